// Round 2
// baseline (378.509 us; speedup 1.0000x reference)
//
#include <hip/hip_runtime.h>
#include <math.h>

// ---------------------------------------------------------------------------
// RecursiveEncoder forward, fp16 MFMA pipeline. Round 2:
//  - leaf encoder MFMA-ized (K=32 zero-padded) instead of f32 vector loop
//  - k2 M=64/block, single act buffer (outputs staged through regs)
//  - kconv loads coalesced (n-fastest), weight row pad 72 -> 68 halfs
// ---------------------------------------------------------------------------

#define NPAR   32768
#define LDA    264          // activation row pad (halfs)
#define LDW    68           // weight-chunk row pad (halfs): 34-dw stride, uniform banks
#define LDBOX  40           // box/Wbox row pad (halfs), K=32 zero-padded
#define CELEMS (256*LDW)    // 17408 halfs per 64-k chunk
#define WELEMS (4*CELEMS)   // 69632 halfs per weight
#define WBOX_OFF (5*WELEMS)         // 348160
#define XBUF_OFF (WBOX_OFF + 256*LDBOX)  // 358400

typedef _Float16 f16;
typedef _Float16 f16x8 __attribute__((ext_vector_type(8)));
typedef float    f32x4 __attribute__((ext_vector_type(4)));

__device__ __forceinline__ void async16(const void* g, void* l) {
    __builtin_amdgcn_global_load_lds((const __attribute__((address_space(1))) void*)g,
                                     (__attribute__((address_space(3))) void*)l, 16, 0, 0);
}
__device__ __forceinline__ f32x4 mfma16(f16x8 a, f16x8 b, f32x4 c) {
    return __builtin_amdgcn_mfma_f32_16x16x32_f16(a, b, c, 0, 0, 0);
}

// ---------------- kconv: weights -> ws (coalesced loads, n fastest) ----------
// main weights: ws[w][c][n][kk<=68] = W[c*64+kk][n]; wboxT[n][kk<=40] = Wbox[kk][n]
__global__ void kconv(const float* __restrict__ W1, const float* __restrict__ W2,
                      const float* __restrict__ Ws1, const float* __restrict__ Wmu,
                      const float* __restrict__ Wvar, const float* __restrict__ Wbox,
                      f16* __restrict__ ws) {
    int idx = blockIdx.x * 256 + threadIdx.x;
    if (idx < 5 * WELEMS) {
        int n = idx & 255, t = idx >> 8;          // t = (w*4+c)*68 + kk
        int kk = t % 68, wc = t / 68;
        int c = wc & 3, wgt = wc >> 2;
        const float* s = W1;
        if (wgt == 1) s = W2; else if (wgt == 2) s = Ws1;
        else if (wgt == 3) s = Wmu; else if (wgt == 4) s = Wvar;
        float v = (kk < 64) ? s[(c * 64 + kk) * 256 + n] : 0.f;
        ws[wgt * WELEMS + c * CELEMS + n * LDW + kk] = (f16)v;
    } else {
        int idx2 = idx - 5 * WELEMS;              // 256*40 WboxT elements
        int n = idx2 & 255, kk = idx2 >> 8;
        float v = (kk < 10) ? Wbox[kk * 256 + n] : 0.f;
        ws[WBOX_OFF + n * LDBOX + kk] = (f16)v;
    }
}

// ---------------- k1: leaf MFMA + big GEMM + max-pool ------------------------
// block = 8 parents = 80 child rows; grid 4096; 256 thr (4 waves)
__global__ __launch_bounds__(256, 2)
void k1(const float* __restrict__ box, const float* __restrict__ bbox,
        const float* __restrict__ W1, const float* __restrict__ b1,
        const int* __restrict__ sem, const int* __restrict__ nch,
        const f16* __restrict__ wsh, f16* __restrict__ xbuf) {
    __shared__ __align__(16) char smem[77408];
    f16* lA   = (f16*)smem;                       // [80][264] = 42240 B
    f16* lB   = (f16*)(smem + 42240);             // [256][68] = 34816 B
    f16* wbx  = lB;                               // overlay: wboxT [256][40] = 20480 B
    f16* boxA = (f16*)(smem + 42240 + 21504);     // overlay: [80][40] = 6400 B (21504..27904)
    int* lsem = (int*)(smem + 77056);             // 80 ints
    int* lnc  = (int*)(smem + 77376);             // 8 ints

    int tid = threadIdx.x, blk = blockIdx.x;
    const f16* w1t   = wsh;
    const f16* wboxg = wsh + WBOX_OFF;

    // stage wboxT (flat 20480 B) + boxA (f32->f16, zero-pad k>=10) + sem/nch
    #pragma unroll
    for (int j = 0; j < 5; j++) { int o = (tid + j * 256) * 16; async16((const char*)wboxg + o, (char*)wbx + o); }
    for (int i = tid; i < 3200; i += 256) {
        int r = i / LDBOX, k = i % LDBOX;
        boxA[i] = (k < 10) ? (f16)box[(size_t)blk * 800 + r * 10 + k] : (f16)0.f;
    }
    if (tid < 80) lsem[tid] = sem[blk * 80 + tid];
    if (tid < 8)  lnc[tid]  = nch[blk * 8 + tid];
    __syncthreads();                              // drains wboxT vmcnt too

    int w = tid >> 6, lane = tid & 63, q = lane >> 4, r16 = lane & 15;

    // leaf = relu(box @ Wbox + bbox) via one K=32 MFMA round -> lA (f16 A-layout)
    {
        f32x4 accL[5][4];
        f16x8 a[5], b[4];
        #pragma unroll
        for (int mt = 0; mt < 5; mt++)
            a[mt] = *(const f16x8*)&boxA[(mt * 16 + r16) * LDBOX + q * 8];
        #pragma unroll
        for (int nt = 0; nt < 4; nt++)
            b[nt] = *(const f16x8*)&wbx[(w * 64 + nt * 16 + r16) * LDBOX + q * 8];
        #pragma unroll
        for (int mt = 0; mt < 5; mt++)
            #pragma unroll
            for (int nt = 0; nt < 4; nt++)
                accL[mt][nt] = mfma16(a[mt], b[nt], (f32x4){0.f, 0.f, 0.f, 0.f});
        #pragma unroll
        for (int nt = 0; nt < 4; nt++) {
            int col = w * 64 + nt * 16 + r16;
            float bv = bbox[col];
            #pragma unroll
            for (int mt = 0; mt < 5; mt++)
                #pragma unroll
                for (int i = 0; i < 4; i++) {
                    int row = mt * 16 + q * 4 + i;
                    lA[row * LDA + col] = (f16)fmaxf(accL[mt][nt][i] + bv, 0.f);
                }
        }
    }

    f32x4 acc[5][4];
    #pragma unroll
    for (int mt = 0; mt < 5; mt++)
        #pragma unroll
        for (int nt = 0; nt < 4; nt++) acc[mt][nt] = (f32x4){0.f, 0.f, 0.f, 0.f};

    // K loop: feat_pre = leaf @ W1[0:256]
    for (int c = 0; c < 4; c++) {
        __syncthreads();                          // prev chunk consumed (c=0: wbx/boxA dead)
        {
            const char* src = (const char*)(w1t + c * CELEMS);
            char* dst = (char*)lB;
            #pragma unroll
            for (int j = 0; j < 9; j++) {
                int idx = tid + j * 256;
                if (idx < 2176) async16(src + idx * 16, dst + idx * 16);
            }
        }
        __syncthreads();                          // drains vmcnt
        #pragma unroll
        for (int k32 = 0; k32 < 64; k32 += 32) {
            f16x8 a[5], b[4];
            #pragma unroll
            for (int mt = 0; mt < 5; mt++)
                a[mt] = *(const f16x8*)&lA[(mt * 16 + r16) * LDA + c * 64 + k32 + q * 8];
            #pragma unroll
            for (int nt = 0; nt < 4; nt++)
                b[nt] = *(const f16x8*)&lB[(w * 64 + nt * 16 + r16) * LDW + k32 + q * 8];
            #pragma unroll
            for (int mt = 0; mt < 5; mt++)
                #pragma unroll
                for (int nt = 0; nt < 4; nt++) acc[mt][nt] = mfma16(a[mt], b[nt], acc[mt][nt]);
        }
    }
    __syncthreads();                              // all A reads done before overwrite

    // epilogue: + b1 + one-hot sem row of W1, relu -> lA (f16)
    #pragma unroll
    for (int mt = 0; mt < 5; mt++)
        #pragma unroll
        for (int nt = 0; nt < 4; nt++) {
            int col = w * 64 + nt * 16 + r16;
            float bv = b1[col];
            #pragma unroll
            for (int i = 0; i < 4; i++) {
                int row = mt * 16 + q * 4 + i;
                int sid = lsem[row];
                float v = acc[mt][nt][i] + bv + W1[(256 + sid) * 256 + col];
                lA[row * LDA + col] = (f16)fmaxf(v, 0.f);
            }
        }
    __syncthreads();

    // masked max over children -> xbuf (padded f16 rows)
    for (int p = 0; p < 8; p++) {
        int nc = lnc[p];
        float v = 0.f;
        for (int m = 0; m < nc; m++) v = fmaxf(v, (float)lA[(p * 10 + m) * LDA + tid]);
        xbuf[((size_t)blk * 8 + p) * LDA + tid] = (f16)v;
    }
}

// ---------------- k2: sampler chain, M=64/block ------------------------------
// block = 64 parents; grid 512 (exactly one residency round); 256 thr
__global__ __launch_bounds__(256, 2)
void k2(const f16* __restrict__ xbuf, const f16* __restrict__ wsh,
        const float* __restrict__ b2, const float* __restrict__ bs1,
        const float* __restrict__ bmu, const float* __restrict__ bvar,
        const float* __restrict__ eps, float* __restrict__ out) {
    __shared__ __align__(16) char smem[68608];
    f16* actX = (f16*)smem;                 // [64][264] = 33792 B (ping-pong via regs)
    f16* wbuf = (f16*)(smem + 33792);       // [256][68] = 34816 B

    int tid = threadIdx.x, blk = blockIdx.x;
    int w = tid >> 6, lane = tid & 63, q = lane >> 4, r16 = lane & 15;

    {   // stage x tile (flat 33792 B); drained by gemm1's first barrier
        const char* src = (const char*)(xbuf + (size_t)blk * 64 * LDA);
        #pragma unroll
        for (int j = 0; j < 9; j++) {
            int idx = tid + j * 256;
            if (idx < 2112) async16(src + idx * 16, (char*)actX + idx * 16);
        }
    }

    f32x4 acc[4][4];
    auto gemm = [&](const f16* Wc) {
        #pragma unroll
        for (int mt = 0; mt < 4; mt++)
            #pragma unroll
            for (int nt = 0; nt < 4; nt++) acc[mt][nt] = (f32x4){0.f, 0.f, 0.f, 0.f};
        for (int c = 0; c < 4; c++) {
            __syncthreads();
            {
                const char* src = (const char*)(Wc + c * CELEMS);
                char* dst = (char*)wbuf;
                #pragma unroll
                for (int j = 0; j < 9; j++) {
                    int idx = tid + j * 256;
                    if (idx < 2176) async16(src + idx * 16, dst + idx * 16);
                }
            }
            __syncthreads();
            #pragma unroll
            for (int k32 = 0; k32 < 64; k32 += 32) {
                f16x8 a[4], b[4];
                #pragma unroll
                for (int mt = 0; mt < 4; mt++)
                    a[mt] = *(const f16x8*)&actX[(mt * 16 + r16) * LDA + c * 64 + k32 + q * 8];
                #pragma unroll
                for (int nt = 0; nt < 4; nt++)
                    b[nt] = *(const f16x8*)&wbuf[(w * 64 + nt * 16 + r16) * LDW + k32 + q * 8];
                #pragma unroll
                for (int mt = 0; mt < 4; mt++)
                    #pragma unroll
                    for (int nt = 0; nt < 4; nt++) acc[mt][nt] = mfma16(a[mt], b[nt], acc[mt][nt]);
            }
        }
    };

    const f16* W2t   = wsh + WELEMS;
    const f16* Ws1t  = wsh + 2 * WELEMS;
    const f16* Wmut  = wsh + 3 * WELEMS;
    const f16* Wvart = wsh + 4 * WELEMS;

    // GEMM1: parent = relu(x @ W2 + b2) -> actX (in place, via regs)
    gemm(W2t);
    __syncthreads();                        // all reads of x done before overwrite
    #pragma unroll
    for (int nt = 0; nt < 4; nt++) {
        int col = w * 64 + nt * 16 + r16;
        float bv = b2[col];
        #pragma unroll
        for (int mt = 0; mt < 4; mt++)
            #pragma unroll
            for (int i = 0; i < 4; i++)
                actX[(mt * 16 + q * 4 + i) * LDA + col] = (f16)fmaxf(acc[mt][nt][i] + bv, 0.f);
    }

    // GEMM2: enc = relu(parent @ Ws1 + bs1) -> actX
    gemm(Ws1t);
    __syncthreads();
    #pragma unroll
    for (int nt = 0; nt < 4; nt++) {
        int col = w * 64 + nt * 16 + r16;
        float bv = bs1[col];
        #pragma unroll
        for (int mt = 0; mt < 4; mt++)
            #pragma unroll
            for (int i = 0; i < 4; i++)
                actX[(mt * 16 + q * 4 + i) * LDA + col] = (f16)fmaxf(acc[mt][nt][i] + bv, 0.f);
    }

    // GEMM3: mu (keep in regs); GEMM4: logvar + fused sampler epilogue
    gemm(Wmut);
    f32x4 mu[4][4];
    #pragma unroll
    for (int mt = 0; mt < 4; mt++)
        #pragma unroll
        for (int nt = 0; nt < 4; nt++) mu[mt][nt] = acc[mt][nt];

    gemm(Wvart);
    #pragma unroll
    for (int mt = 0; mt < 4; mt++)
        #pragma unroll
        for (int nt = 0; nt < 4; nt++) {
            int col = w * 64 + nt * 16 + r16;
            float bm = bmu[col], bv = bvar[col];
            #pragma unroll
            for (int i = 0; i < 4; i++) {
                int row = mt * 16 + q * 4 + i;
                size_t grow = (size_t)blk * 64 + row;
                float m_ = mu[mt][nt][i] + bm;
                float lv = acc[mt][nt][i] + bv;
                float e  = expf(lv);
                out[grow * 512 + col]       = eps[grow * 256 + col] * sqrtf(e) + m_;
                out[grow * 512 + 256 + col] = 1.f + lv - m_ * m_ - e;
            }
        }
}

// ---------------------------------------------------------------------------
extern "C" void kernel_launch(void* const* d_in, const int* in_sizes, int n_in,
                              void* d_out, int out_size, void* d_ws, size_t ws_size,
                              hipStream_t stream) {
    const float* box  = (const float*)d_in[0];
    const float* eps  = (const float*)d_in[1];
    const float* Wbox = (const float*)d_in[2];
    const float* bbox = (const float*)d_in[3];
    const float* W1   = (const float*)d_in[4];
    const float* b1   = (const float*)d_in[5];
    const float* W2   = (const float*)d_in[6];
    const float* b2   = (const float*)d_in[7];
    const float* Ws1  = (const float*)d_in[8];
    const float* bs1  = (const float*)d_in[9];
    const float* Wmu  = (const float*)d_in[10];
    const float* bmu  = (const float*)d_in[11];
    const float* Wvar = (const float*)d_in[12];
    const float* bvar = (const float*)d_in[13];
    const int*   sem  = (const int*)d_in[14];
    const int*   nch  = (const int*)d_in[15];

    f16* wsh  = (f16*)d_ws;
    f16* xbuf = wsh + XBUF_OFF;

    // 5*WELEMS + 256*40 = 358400 elements -> 1400 blocks exactly
    kconv<<<1400, 256, 0, stream>>>(W1, W2, Ws1, Wmu, Wvar, Wbox, wsh);
    k1<<<NPAR / 8, 256, 0, stream>>>(box, bbox, W1, b1, sem, nch, wsh, xbuf);
    k2<<<NPAR / 64, 256, 0, stream>>>(xbuf, wsh, b2, bs1, bmu, bvar, eps, (float*)d_out);
}

// Round 3
// 289.388 us; speedup vs baseline: 1.3080x; 1.3080x over previous
//
#include <hip/hip_runtime.h>
#include <math.h>

// ---------------------------------------------------------------------------
// RecursiveEncoder forward, fp16 MFMA pipeline. Round 3:
//  - NO weight staging in LDS: B-fragments stream global->registers,
//    software-pipelined 3 k32-iters deep (rotating 3x4 frag buffer).
//    Eliminates all per-chunk vmcnt(0)-drain barriers (k1: 10->3, k2: 16+->4).
//  - sem one-hot folded into the GEMM: lA has K=320 (cols 256..319 = one-hot),
//    W1^T stored full 320 rows. Removes 80 scalar gather loads/thread.
//  - dense unpadded W^T (64B-line coalesced frag loads; no LDS banks involved).
// ---------------------------------------------------------------------------

#define NPAR  32768
#define LDA1  328        // k1 activation row (halfs): K=320 + 8 pad
#define LDA2  264        // k2 activation row (halfs): K=256 + 8 pad
// ws layout (halfs):
#define W1T_OFF   0                  // [256][320]
#define W2T_OFF   81920              // 4 x [256][256]
#define WBX_OFF   (81920 + 4*65536)  // [256][32]  = 344064
#define XBUF_OFF  (WBX_OFF + 8192)   // = 352256; [NPAR][264]

typedef _Float16 f16;
typedef _Float16 f16x8 __attribute__((ext_vector_type(8)));
typedef float    f32x4 __attribute__((ext_vector_type(4)));

__device__ __forceinline__ void async16(const void* g, void* l) {
    __builtin_amdgcn_global_load_lds((const __attribute__((address_space(1))) void*)g,
                                     (__attribute__((address_space(3))) void*)l, 16, 0, 0);
}
__device__ __forceinline__ f32x4 mfma16(f16x8 a, f16x8 b, f32x4 c) {
    return __builtin_amdgcn_mfma_f32_16x16x32_f16(a, b, c, 0, 0, 0);
}

// ---------------- kconv: dense transposed f16 weights ------------------------
__global__ void kconv(const float* __restrict__ W1, const float* __restrict__ W2,
                      const float* __restrict__ Ws1, const float* __restrict__ Wmu,
                      const float* __restrict__ Wvar, const float* __restrict__ Wbox,
                      f16* __restrict__ ws) {
    int idx = blockIdx.x * 256 + threadIdx.x;
    if (idx < 81920) {                       // W1T[n][k] = W1[k][n], k<320
        int k = idx >> 8, n = idx & 255;
        ws[W1T_OFF + n * 320 + k] = (f16)W1[idx];
    } else if (idx < WBX_OFF) {
        int r = idx - 81920;
        int wsel = r >> 16, r2 = r & 65535;
        int k = r2 >> 8, n = r2 & 255;
        const float* s = (wsel == 0) ? W2 : (wsel == 1) ? Ws1 : (wsel == 2) ? Wmu : Wvar;
        ws[W2T_OFF + wsel * 65536 + n * 256 + k] = (f16)s[r2];
    } else if (idx < XBUF_OFF) {             // WboxT[n][32], zero-padded k>=10
        int r = idx - WBX_OFF;
        int k = r >> 8, n = r & 255;
        float v = (k < 10) ? Wbox[r] : 0.f;
        ws[WBX_OFF + n * 32 + k] = (f16)v;
    }
}

// ---------------- k1: leaf MFMA + K=320 GEMM (one-hot fused) + max-pool ------
// block = 8 parents = 80 rows; grid 4096; 256 thr (4 waves, each N=64)
__global__ __launch_bounds__(256, 2)
void k1(const float* __restrict__ box, const float* __restrict__ bbox,
        const float* __restrict__ b1, const int* __restrict__ sem,
        const int* __restrict__ nch, const f16* __restrict__ wsh,
        f16* __restrict__ xbuf) {
    __shared__ __align__(16) f16 lA[80 * LDA1];   // 52480 B
    __shared__ int lnc[8];

    int tid = threadIdx.x, blk = blockIdx.x;
    int w = tid >> 6, lane = tid & 63, q = lane >> 4, r16 = lane & 15;
    const f16* w1t = wsh + W1T_OFF;
    const f16* wbx = wsh + WBX_OFF;

    if (tid < 8) lnc[tid] = nch[blk * 8 + tid];

    float bbv[4], b1v[4];
    #pragma unroll
    for (int nt = 0; nt < 4; nt++) {
        int col = w * 64 + nt * 16 + r16;
        bbv[nt] = bbox[col];
        b1v[nt] = b1[col];
    }

    // ---- leaf: relu(box @ Wbox + bbox), K=32 zero-padded, frags from global
    f32x4 acc[5][4];
    {
        f16x8 bb[4], ab[5];
        #pragma unroll
        for (int nt = 0; nt < 4; nt++)
            bb[nt] = *(const f16x8*)&wbx[(w * 64 + nt * 16 + r16) * 32 + q * 8];
        #pragma unroll
        for (int mt = 0; mt < 5; mt++) {
            const float* bp = box + (size_t)blk * 800 + (mt * 16 + r16) * 10;
            float v[8] = {0.f, 0.f, 0.f, 0.f, 0.f, 0.f, 0.f, 0.f};
            if (q == 0) {
                float2 t0 = *(const float2*)(bp + 0), t1 = *(const float2*)(bp + 2);
                float2 t2 = *(const float2*)(bp + 4), t3 = *(const float2*)(bp + 6);
                v[0] = t0.x; v[1] = t0.y; v[2] = t1.x; v[3] = t1.y;
                v[4] = t2.x; v[5] = t2.y; v[6] = t3.x; v[7] = t3.y;
            } else if (q == 1) {
                float2 t = *(const float2*)(bp + 8);
                v[0] = t.x; v[1] = t.y;
            }
            f16x8 t;
            #pragma unroll
            for (int j = 0; j < 8; j++) t[j] = (f16)v[j];
            ab[mt] = t;
        }
        #pragma unroll
        for (int mt = 0; mt < 5; mt++)
            #pragma unroll
            for (int nt = 0; nt < 4; nt++)
                acc[mt][nt] = mfma16(ab[mt], bb[nt], (f32x4){0.f, 0.f, 0.f, 0.f});
    }
    // leaf -> lA (C-layout scatter, f16)
    #pragma unroll
    for (int nt = 0; nt < 4; nt++) {
        int col = w * 64 + nt * 16 + r16;
        #pragma unroll
        for (int mt = 0; mt < 5; mt++)
            #pragma unroll
            for (int i = 0; i < 4; i++)
                lA[(mt * 16 + q * 4 + i) * LDA1 + col] = (f16)fmaxf(acc[mt][nt][i] + bbv[nt], 0.f);
    }
    // one-hot region k=256..319 (each row owned by one thread: no races)
    if (tid < 80) {
        int sid = sem[blk * 80 + tid];
        f16x8 z = {(f16)0.f, (f16)0.f, (f16)0.f, (f16)0.f, (f16)0.f, (f16)0.f, (f16)0.f, (f16)0.f};
        #pragma unroll
        for (int j = 0; j < 8; j++) *(f16x8*)&lA[tid * LDA1 + 256 + j * 8] = z;
        lA[tid * LDA1 + 256 + sid] = (f16)1.f;
    }

    // ---- main GEMM: K=320, B streamed global->regs, 3-deep pipeline
    #pragma unroll
    for (int mt = 0; mt < 5; mt++)
        #pragma unroll
        for (int nt = 0; nt < 4; nt++) acc[mt][nt] = (f32x4){0.f, 0.f, 0.f, 0.f};

    f16x8 bs[3][4];
    auto loadB = [&](int c, int s) {
        #pragma unroll
        for (int nt = 0; nt < 4; nt++)
            bs[s][nt] = *(const f16x8*)&w1t[(w * 64 + nt * 16 + r16) * 320 + c * 32 + q * 8];
    };
    loadB(0, 0); loadB(1, 1); loadB(2, 2);
    __syncthreads();                               // lA (leaf + one-hot) visible
    #pragma unroll
    for (int c = 0; c < 10; c++) {
        f16x8 a[5];
        #pragma unroll
        for (int mt = 0; mt < 5; mt++)
            a[mt] = *(const f16x8*)&lA[(mt * 16 + r16) * LDA1 + c * 32 + q * 8];
        int s = c % 3;
        #pragma unroll
        for (int mt = 0; mt < 5; mt++)
            #pragma unroll
            for (int nt = 0; nt < 4; nt++) acc[mt][nt] = mfma16(a[mt], bs[s][nt], acc[mt][nt]);
        if (c + 3 < 10) loadB(c + 3, s);
    }
    __syncthreads();                               // all lA reads done

    // epilogue: +b1, relu -> lA (rows reused as [80][256] feat)
    #pragma unroll
    for (int nt = 0; nt < 4; nt++) {
        int col = w * 64 + nt * 16 + r16;
        #pragma unroll
        for (int mt = 0; mt < 5; mt++)
            #pragma unroll
            for (int i = 0; i < 4; i++)
                lA[(mt * 16 + q * 4 + i) * LDA1 + col] = (f16)fmaxf(acc[mt][nt][i] + b1v[nt], 0.f);
    }
    __syncthreads();

    // masked max over children -> xbuf
    #pragma unroll
    for (int p = 0; p < 8; p++) {
        int nc = lnc[p];
        float v = 0.f;
        for (int m = 0; m < nc; m++) v = fmaxf(v, (float)lA[(p * 10 + m) * LDA1 + tid]);
        xbuf[((size_t)blk * 8 + p) * LDA2 + tid] = (f16)v;
    }
}

// ---------------- k2: sampler chain, M=32/block, B streamed to regs ----------
// grid 1024; 256 thr; LDS = 2 x 16896 B only
__global__ __launch_bounds__(256, 2)
void k2(const f16* __restrict__ xbuf, const f16* __restrict__ wsh,
        const float* __restrict__ b2, const float* __restrict__ bs1,
        const float* __restrict__ bmu, const float* __restrict__ bvar,
        const float* __restrict__ eps, float* __restrict__ out) {
    __shared__ __align__(16) f16 actA[32 * LDA2];
    __shared__ __align__(16) f16 actB[32 * LDA2];

    int tid = threadIdx.x, blk = blockIdx.x;
    int w = tid >> 6, lane = tid & 63, q = lane >> 4, r16 = lane & 15;
    const f16* w2t   = wsh + W2T_OFF;
    const f16* ws1t  = w2t + 65536;
    const f16* wmut  = w2t + 2 * 65536;
    const f16* wvart = w2t + 3 * 65536;

    float b2v[4], bs1v[4], bmv[4], bvv[4];
    #pragma unroll
    for (int nt = 0; nt < 4; nt++) {
        int col = w * 64 + nt * 16 + r16;
        b2v[nt] = b2[col]; bs1v[nt] = bs1[col];
        bmv[nt] = bmu[col]; bvv[nt] = bvar[col];
    }

    {   // stage x tile (16896 B flat) -> actA
        const char* src = (const char*)(xbuf + (size_t)blk * 32 * LDA2);
        #pragma unroll
        for (int j = 0; j < 5; j++) {
            int idx = tid + j * 256;
            if (idx < 1056) async16(src + idx * 16, (char*)actA + idx * 16);
        }
    }

    f32x4 acc[2][4];
    f16x8 bs[3][4];
    auto loadB = [&](const f16* wt, int c, int s) {
        #pragma unroll
        for (int nt = 0; nt < 4; nt++)
            bs[s][nt] = *(const f16x8*)&wt[(w * 64 + nt * 16 + r16) * 256 + c * 32 + q * 8];
    };
    auto gemm = [&](const f16* A, const f16* wt) {   // caller preloads bs[0..2]
        #pragma unroll
        for (int mt = 0; mt < 2; mt++)
            #pragma unroll
            for (int nt = 0; nt < 4; nt++) acc[mt][nt] = (f32x4){0.f, 0.f, 0.f, 0.f};
        #pragma unroll
        for (int c = 0; c < 8; c++) {
            f16x8 a[2];
            #pragma unroll
            for (int mt = 0; mt < 2; mt++)
                a[mt] = *(const f16x8*)&A[(mt * 16 + r16) * LDA2 + c * 32 + q * 8];
            int s = c % 3;
            #pragma unroll
            for (int mt = 0; mt < 2; mt++)
                #pragma unroll
                for (int nt = 0; nt < 4; nt++) acc[mt][nt] = mfma16(a[mt], bs[s][nt], acc[mt][nt]);
            if (c + 3 < 8) loadB(wt, c + 3, s);
        }
    };

    // stage1: parent = relu(x @ W2 + b2) -> actB
    loadB(w2t, 0, 0); loadB(w2t, 1, 1); loadB(w2t, 2, 2);
    __syncthreads();                               // drains actA staging
    gemm(actA, w2t);
    #pragma unroll
    for (int nt = 0; nt < 4; nt++) {
        int col = w * 64 + nt * 16 + r16;
        #pragma unroll
        for (int mt = 0; mt < 2; mt++)
            #pragma unroll
            for (int i = 0; i < 4; i++)
                actB[(mt * 16 + q * 4 + i) * LDA2 + col] = (f16)fmaxf(acc[mt][nt][i] + b2v[nt], 0.f);
    }
    loadB(ws1t, 0, 0); loadB(ws1t, 1, 1); loadB(ws1t, 2, 2);
    __syncthreads();

    // stage2: enc = relu(parent @ Ws1 + bs1) -> actA
    gemm(actB, ws1t);
    #pragma unroll
    for (int nt = 0; nt < 4; nt++) {
        int col = w * 64 + nt * 16 + r16;
        #pragma unroll
        for (int mt = 0; mt < 2; mt++)
            #pragma unroll
            for (int i = 0; i < 4; i++)
                actA[(mt * 16 + q * 4 + i) * LDA2 + col] = (f16)fmaxf(acc[mt][nt][i] + bs1v[nt], 0.f);
    }
    loadB(wmut, 0, 0); loadB(wmut, 1, 1); loadB(wmut, 2, 2);
    __syncthreads();

    // stage3: mu -> regs
    gemm(actA, wmut);
    f32x4 mu[2][4];
    #pragma unroll
    for (int mt = 0; mt < 2; mt++)
        #pragma unroll
        for (int nt = 0; nt < 4; nt++) mu[mt][nt] = acc[mt][nt];

    // prefetch eps while stage4 runs
    float ev[2][4][4];
    #pragma unroll
    for (int mt = 0; mt < 2; mt++)
        #pragma unroll
        for (int i = 0; i < 4; i++) {
            size_t grow = (size_t)blk * 32 + mt * 16 + q * 4 + i;
            #pragma unroll
            for (int nt = 0; nt < 4; nt++)
                ev[mt][nt][i] = eps[grow * 256 + w * 64 + nt * 16 + r16];
        }

    // stage4: logvar + fused sampler epilogue (actA unchanged: no barrier)
    loadB(wvart, 0, 0); loadB(wvart, 1, 1); loadB(wvart, 2, 2);
    gemm(actA, wvart);
    #pragma unroll
    for (int mt = 0; mt < 2; mt++)
        #pragma unroll
        for (int nt = 0; nt < 4; nt++) {
            int col = w * 64 + nt * 16 + r16;
            #pragma unroll
            for (int i = 0; i < 4; i++) {
                size_t grow = (size_t)blk * 32 + mt * 16 + q * 4 + i;
                float m_ = mu[mt][nt][i] + bmv[nt];
                float lv = acc[mt][nt][i] + bvv[nt];
                float e  = expf(lv);
                out[grow * 512 + col]       = ev[mt][nt][i] * sqrtf(e) + m_;
                out[grow * 512 + 256 + col] = 1.f + lv - m_ * m_ - e;
            }
        }
}

// ---------------------------------------------------------------------------
extern "C" void kernel_launch(void* const* d_in, const int* in_sizes, int n_in,
                              void* d_out, int out_size, void* d_ws, size_t ws_size,
                              hipStream_t stream) {
    const float* box  = (const float*)d_in[0];
    const float* eps  = (const float*)d_in[1];
    const float* Wbox = (const float*)d_in[2];
    const float* bbox = (const float*)d_in[3];
    const float* W1   = (const float*)d_in[4];
    const float* b1   = (const float*)d_in[5];
    const float* W2   = (const float*)d_in[6];
    const float* b2   = (const float*)d_in[7];
    const float* Ws1  = (const float*)d_in[8];
    const float* bs1  = (const float*)d_in[9];
    const float* Wmu  = (const float*)d_in[10];
    const float* bmu  = (const float*)d_in[11];
    const float* Wvar = (const float*)d_in[12];
    const float* bvar = (const float*)d_in[13];
    const int*   sem  = (const int*)d_in[14];
    const int*   nch  = (const int*)d_in[15];

    f16* wsh  = (f16*)d_ws;
    f16* xbuf = wsh + XBUF_OFF;

    kconv<<<XBUF_OFF / 256, 256, 0, stream>>>(W1, W2, Ws1, Wmu, Wvar, Wbox, wsh);
    k1<<<NPAR / 8, 256, 0, stream>>>(box, bbox, b1, sem, nch, wsh, xbuf);
    k2<<<NPAR / 32, 256, 0, stream>>>(xbuf, wsh, b2, bs1, bmu, bvar, eps, (float*)d_out);
}